// Round 1
// baseline (179.947 us; speedup 1.0000x reference)
//
#include <hip/hip_runtime.h>
#include <hip/hip_bf16.h>

#define NN 8192   // nodes
#define NE 8192   // edges
#define CC 256    // channels
#define CAP 128   // max nnz per row/col (mean ~34, sigma ~5.7 -> 16-sigma safe)

// ---------------- K1: scan incidence rows -> fixed-stride CSR + row counts ----
__global__ __launch_bounds__(256) void k1_scan_rows(const float* __restrict__ B,
                                                    int* __restrict__ csr,
                                                    int* __restrict__ row_cnt) {
    const int wave = threadIdx.x >> 6;
    const int lane = threadIdx.x & 63;
    const int row  = blockIdx.x * 4 + wave;
    const float4* rp = (const float4*)(B + (size_t)row * NE);
    int* outp = csr + (size_t)row * CAP;
    int base = 0;
    for (int it = 0; it < NE / 4 / 64; ++it) {           // 32 iterations
        float4 v = rp[it * 64 + lane];
        int m = (v.x != 0.f) + (v.y != 0.f) + (v.z != 0.f) + (v.w != 0.f);
        unsigned long long any = __ballot(m > 0);
        if (any == 0ull) continue;
        // inclusive wave prefix sum of m
        int pref = m;
        #pragma unroll
        for (int d = 1; d < 64; d <<= 1) {
            int o = __shfl_up(pref, d);
            if (lane >= d) pref += o;
        }
        int total = __shfl(pref, 63);
        int pos = base + pref - m;                        // exclusive prefix
        int e0 = (it * 64 + lane) * 4;
        if (v.x != 0.f && pos < CAP) outp[pos++] = e0;
        if (v.y != 0.f && pos < CAP) outp[pos++] = e0 + 1;
        if (v.z != 0.f && pos < CAP) outp[pos++] = e0 + 2;
        if (v.w != 0.f && pos < CAP) outp[pos++] = e0 + 3;
        base += total;
    }
    if (lane == 0) row_cnt[row] = base < CAP ? base : CAP;
}

// ---------------- K2: CSR -> CSC scatter + weighted edge degree sums ----------
__global__ __launch_bounds__(256) void k2_scatter(const int* __restrict__ csr,
                                                  const int* __restrict__ row_cnt,
                                                  int* __restrict__ col_cnt,
                                                  int* __restrict__ csc,
                                                  float* __restrict__ edge_wsum) {
    const int wave = threadIdx.x >> 6;
    const int lane = threadIdx.x & 63;
    const int row  = blockIdx.x * 4 + wave;
    const int cnt  = row_cnt[row];
    const float deg = (float)cnt;
    for (int i = lane; i < cnt; i += 64) {
        int e = csr[(size_t)row * CAP + i];
        int pos = atomicAdd(&col_cnt[e], 1);
        if (pos < CAP) csc[(size_t)e * CAP + pos] = row;
        atomicAdd(&edge_wsum[e], deg);   // integer-valued: order-independent exact
    }
}

// ---------------- K3: normalizers --------------------------------------------
__global__ void k3_norm(const int* __restrict__ row_cnt, const int* __restrict__ col_cnt,
                        const float* __restrict__ edge_wsum,
                        float* __restrict__ er, float* __restrict__ nr) {
    int i = blockIdx.x * blockDim.x + threadIdx.x;
    if (i < NE) {
        float cs = (float)col_cnt[i];        // >=1 (diagonal)
        er[i] = rsqrtf(edge_wsum[i] / cs);
    }
    if (i < NN) nr[i] = rsqrtf((float)row_cnt[i]);
}

// ---------------- K4: edge aggregation m01s[e][:] = er[e] * sum x[n][:] -------
__global__ __launch_bounds__(256) void k4_edge_agg(const float* __restrict__ x0,
                                                   const int* __restrict__ csc,
                                                   const int* __restrict__ col_cnt,
                                                   const float* __restrict__ er,
                                                   float* __restrict__ m01s) {
    const int e = blockIdx.x;
    int cnt = col_cnt[e];
    if (cnt > CAP) cnt = CAP;
    __shared__ int nl[CAP];
    if ((int)threadIdx.x < cnt) nl[threadIdx.x] = csc[(size_t)e * CAP + threadIdx.x];
    __syncthreads();
    const int c = threadIdx.x;
    float s0 = 0.f, s1 = 0.f;
    int i = 0;
    for (; i + 2 <= cnt; i += 2) {
        s0 += x0[(size_t)nl[i]     * CC + c];
        s1 += x0[(size_t)nl[i + 1] * CC + c];
    }
    if (i < cnt) s0 += x0[(size_t)nl[i] * CC + c];
    m01s[(size_t)e * CC + c] = (s0 + s1) * er[e];
}

// ---------------- K5: node aggregation + skip --------------------------------
__global__ __launch_bounds__(256) void k5_node_agg(const float* __restrict__ x0,
                                                   const float* __restrict__ m01s,
                                                   const int* __restrict__ csr,
                                                   const int* __restrict__ row_cnt,
                                                   const float* __restrict__ nr,
                                                   float* __restrict__ xc) {
    const int n = blockIdx.x;
    const int cnt = row_cnt[n];
    __shared__ int el[CAP];
    if ((int)threadIdx.x < cnt) el[threadIdx.x] = csr[(size_t)n * CAP + threadIdx.x];
    __syncthreads();
    const int c = threadIdx.x;
    float s0 = 0.f, s1 = 0.f;
    int i = 0;
    for (; i + 2 <= cnt; i += 2) {
        s0 += m01s[(size_t)el[i]     * CC + c];
        s1 += m01s[(size_t)el[i + 1] * CC + c];
    }
    if (i < cnt) s0 += m01s[(size_t)el[i] * CC + c];
    // x_combined = 0.9*m_1_0 + 0.1*x_0
    xc[(size_t)n * CC + c] = 0.9f * nr[n] * (s0 + s1) + 0.1f * x0[(size_t)n * CC + c];
}

// ---------------- K6: out = 0.5*xc + 0.5 * xc @ W^T --------------------------
// fp32 register-tiled GEMM: 64x64 tile, 256 threads, 4x4 per thread, K chunks of 16
__global__ __launch_bounds__(256) void k6_gemm(const float* __restrict__ xc,
                                               const float* __restrict__ W,
                                               float* __restrict__ out) {
    __shared__ float As[16][65];   // As[k][m]
    __shared__ float Bs[16][65];   // Bs[k][j]
    const int bm = blockIdx.x * 64;
    const int bn = blockIdx.y * 64;
    const int t  = threadIdx.x;
    const int tx = t & 15;          // col group
    const int ty = t >> 4;          // row group
    const int lr = t >> 2;          // 0..63: tile row for loads
    const int lk = (t & 3) << 2;    // 0,4,8,12: k offset for loads
    float acc[4][4] = {};
    for (int k0 = 0; k0 < CC; k0 += 16) {
        float4 va = *(const float4*)(xc + (size_t)(bm + lr) * CC + k0 + lk);
        float4 vb = *(const float4*)(W  + (size_t)(bn + lr) * CC + k0 + lk);
        As[lk + 0][lr] = va.x; As[lk + 1][lr] = va.y; As[lk + 2][lr] = va.z; As[lk + 3][lr] = va.w;
        Bs[lk + 0][lr] = vb.x; Bs[lk + 1][lr] = vb.y; Bs[lk + 2][lr] = vb.z; Bs[lk + 3][lr] = vb.w;
        __syncthreads();
        #pragma unroll
        for (int kk = 0; kk < 16; ++kk) {
            float a[4], b[4];
            #pragma unroll
            for (int i = 0; i < 4; ++i) a[i] = As[kk][ty * 4 + i];
            #pragma unroll
            for (int j = 0; j < 4; ++j) b[j] = Bs[kk][tx * 4 + j];
            #pragma unroll
            for (int i = 0; i < 4; ++i)
                #pragma unroll
                for (int j = 0; j < 4; ++j)
                    acc[i][j] += a[i] * b[j];
        }
        __syncthreads();
    }
    #pragma unroll
    for (int i = 0; i < 4; ++i) {
        #pragma unroll
        for (int j = 0; j < 4; ++j) {
            size_t r = bm + ty * 4 + i;
            size_t c = bn + tx * 4 + j;
            out[r * CC + c] = 0.5f * xc[r * CC + c] + 0.5f * acc[i][j];
        }
    }
}

// ---------------- launch ------------------------------------------------------
extern "C" void kernel_launch(void* const* d_in, const int* in_sizes, int n_in,
                              void* d_out, int out_size, void* d_ws, size_t ws_size,
                              hipStream_t stream) {
    const float* x0 = (const float*)d_in[0];
    const float* B  = (const float*)d_in[1];
    const float* W  = (const float*)d_in[2];
    float* out = (float*)d_out;

    // workspace layout
    char* ws = (char*)d_ws;
    const size_t need = (24ull << 20) + 5ull * NE * 4 + 1024;
    if (ws_size < need) return;  // insufficient scratch -> fail loudly via wrong output

    int*   csr       = (int*)(ws);                  // 4 MB
    int*   csc       = (int*)(ws + (4ull << 20));   // 4 MB
    float* m01s      = (float*)(ws + (8ull << 20)); // 8 MB
    float* xc        = (float*)(ws + (16ull << 20));// 8 MB
    int*   row_cnt   = (int*)(ws + (24ull << 20));  // 32 KB
    int*   col_cnt   = row_cnt + NN;                // 32 KB
    float* edge_wsum = (float*)(col_cnt + NE);      // 32 KB
    float* er        = edge_wsum + NE;              // 32 KB
    float* nr        = er + NE;                     // 32 KB

    hipMemsetAsync(col_cnt, 0, NE * sizeof(int), stream);
    hipMemsetAsync(edge_wsum, 0, NE * sizeof(float), stream);

    k1_scan_rows<<<NN / 4, 256, 0, stream>>>(B, csr, row_cnt);
    k2_scatter<<<NN / 4, 256, 0, stream>>>(csr, row_cnt, col_cnt, csc, edge_wsum);
    k3_norm<<<(NE + 255) / 256, 256, 0, stream>>>(row_cnt, col_cnt, edge_wsum, er, nr);
    k4_edge_agg<<<NE, 256, 0, stream>>>(x0, csc, col_cnt, er, m01s);
    k5_node_agg<<<NN, 256, 0, stream>>>(x0, m01s, csr, row_cnt, nr, xc);
    dim3 g6(NN / 64, CC / 64);
    k6_gemm<<<g6, 256, 0, stream>>>(xc, W, out);
}

// Round 2
// 142.047 us; speedup vs baseline: 1.2668x; 1.2668x over previous
//
#include <hip/hip_runtime.h>
#include <hip/hip_bf16.h>

#define NN 8192   // nodes
#define NE 8192   // edges
#define CC 256    // channels
#define CAP 128   // max nnz per row/col (mean ~34, sigma ~5.7)

// ---- K1: scan incidence rows -> CSR + row counts, then scatter -> CSC + edge_wsum
// Order within a row/column is irrelevant (only permutes fp sums within tolerance),
// so use ballot+popcount instead of a shfl prefix-scan chain.
__global__ __launch_bounds__(256) void k1_scan(const float* __restrict__ B,
                                               int* __restrict__ csr,
                                               int* __restrict__ row_cnt,
                                               int* __restrict__ col_cnt,
                                               int* __restrict__ csc,
                                               float* __restrict__ edge_wsum) {
    const int wave = threadIdx.x >> 6;
    const int lane = threadIdx.x & 63;
    const int row  = blockIdx.x * 4 + wave;
    const float4* rp = (const float4*)(B + (size_t)row * NE);
    int* outp = csr + (size_t)row * CAP;
    const unsigned long long mlt = (1ull << lane) - 1ull;
    int base = 0;
    for (int it = 0; it < NE / 256; ++it) {            // 32 iterations, 1 KB/wave each
        float4 v = rp[it * 64 + lane];
        unsigned long long bx = __ballot(v.x != 0.f);
        unsigned long long by = __ballot(v.y != 0.f);
        unsigned long long bz = __ballot(v.z != 0.f);
        unsigned long long bw = __ballot(v.w != 0.f);
        if (!(bx | by | bz | bw)) continue;
        int tx = __popcll(bx), ty = __popcll(by), tz = __popcll(bz), tw = __popcll(bw);
        int e0 = (it * 64 + lane) * 4;
        int p;
        if (v.x != 0.f) { p = base + __popcll(bx & mlt);               if (p < CAP) outp[p] = e0;     }
        if (v.y != 0.f) { p = base + tx + __popcll(by & mlt);          if (p < CAP) outp[p] = e0 + 1; }
        if (v.z != 0.f) { p = base + tx + ty + __popcll(bz & mlt);     if (p < CAP) outp[p] = e0 + 2; }
        if (v.w != 0.f) { p = base + tx + ty + tz + __popcll(bw & mlt);if (p < CAP) outp[p] = e0 + 3; }
        base += tx + ty + tz + tw;
    }
    const int cnt = base < CAP ? base : CAP;
    if (lane == 0) row_cnt[row] = cnt;
    const float deg = (float)cnt;
    for (int i = lane; i < cnt; i += 64) {             // fused scatter (csr slice is L1-hot)
        int e = outp[i];
        int pos = atomicAdd(&col_cnt[e], 1);
        if (pos < CAP) csc[(size_t)e * CAP + pos] = row;
        atomicAdd(&edge_wsum[e], deg);                 // integer-valued: exact, order-free
    }
}

// ---- K4: m01s[e][:] = rsqrt(edge_deg) * sum_{n in col e} x0[n][:]
// wave per edge, float4 per lane (1 KB/row-read), indices register-cached + shfl broadcast
__global__ __launch_bounds__(256) void k4_edge_agg(const float* __restrict__ x0,
                                                   const int* __restrict__ csc,
                                                   const int* __restrict__ col_cnt,
                                                   const float* __restrict__ edge_wsum,
                                                   float* __restrict__ m01s) {
    const int wave = threadIdx.x >> 6;
    const int lane = threadIdx.x & 63;
    const int e = blockIdx.x * 4 + wave;
    int cnt = col_cnt[e]; if (cnt > CAP) cnt = CAP;
    const float er = rsqrtf(edge_wsum[e] / (float)cnt);
    const int* cp = csc + (size_t)e * CAP;
    const int idx = cp[lane];                          // first 64 indices in-register
    const float* xb = x0 + lane * 4;
    float ax = 0.f, ay = 0.f, az = 0.f, aw = 0.f;
    float bx2 = 0.f, by2 = 0.f, bz2 = 0.f, bw2 = 0.f;
    const int lim = cnt < 64 ? cnt : 64;
    int i = 0;
    for (; i + 2 <= lim; i += 2) {
        int n0 = __shfl(idx, i), n1 = __shfl(idx, i + 1);
        float4 a = *(const float4*)(xb + (size_t)n0 * CC);
        float4 b = *(const float4*)(xb + (size_t)n1 * CC);
        ax += a.x; ay += a.y; az += a.z; aw += a.w;
        bx2 += b.x; by2 += b.y; bz2 += b.z; bw2 += b.w;
    }
    if (i < lim) {
        int n = __shfl(idx, i);
        float4 a = *(const float4*)(xb + (size_t)n * CC);
        ax += a.x; ay += a.y; az += a.z; aw += a.w;
    }
    for (int j = 64; j < cnt; ++j) {                   // rare (P(cnt>64) ~ 1e-6/edge)
        int n = cp[j];
        float4 a = *(const float4*)(xb + (size_t)n * CC);
        ax += a.x; ay += a.y; az += a.z; aw += a.w;
    }
    float4 r;
    r.x = (ax + bx2) * er; r.y = (ay + by2) * er;
    r.z = (az + bz2) * er; r.w = (aw + bw2) * er;
    *(float4*)(m01s + (size_t)e * CC + lane * 4) = r;
}

// ---- K5: xc[n][:] = 0.9*rsqrt(deg_n)*sum_{e in row n} m01s[e][:] + 0.1*x0[n][:]
__global__ __launch_bounds__(256) void k5_node_agg(const float* __restrict__ x0,
                                                   const float* __restrict__ m01s,
                                                   const int* __restrict__ csr,
                                                   const int* __restrict__ row_cnt,
                                                   float* __restrict__ xc) {
    const int wave = threadIdx.x >> 6;
    const int lane = threadIdx.x & 63;
    const int n = blockIdx.x * 4 + wave;
    const int cnt = row_cnt[n];
    const float nr = rsqrtf((float)cnt);
    const int* ep = csr + (size_t)n * CAP;
    const int idx = ep[lane];
    const float* mb = m01s + lane * 4;
    float ax = 0.f, ay = 0.f, az = 0.f, aw = 0.f;
    float bx2 = 0.f, by2 = 0.f, bz2 = 0.f, bw2 = 0.f;
    const int lim = cnt < 64 ? cnt : 64;
    int i = 0;
    for (; i + 2 <= lim; i += 2) {
        int e0 = __shfl(idx, i), e1 = __shfl(idx, i + 1);
        float4 a = *(const float4*)(mb + (size_t)e0 * CC);
        float4 b = *(const float4*)(mb + (size_t)e1 * CC);
        ax += a.x; ay += a.y; az += a.z; aw += a.w;
        bx2 += b.x; by2 += b.y; bz2 += b.z; bw2 += b.w;
    }
    if (i < lim) {
        int e0 = __shfl(idx, i);
        float4 a = *(const float4*)(mb + (size_t)e0 * CC);
        ax += a.x; ay += a.y; az += a.z; aw += a.w;
    }
    for (int j = 64; j < cnt; ++j) {
        int e0 = ep[j];
        float4 a = *(const float4*)(mb + (size_t)e0 * CC);
        ax += a.x; ay += a.y; az += a.z; aw += a.w;
    }
    float4 x = *(const float4*)(x0 + (size_t)n * CC + lane * 4);
    const float s = 0.9f * nr;
    float4 r;
    r.x = s * (ax + bx2) + 0.1f * x.x;
    r.y = s * (ay + by2) + 0.1f * x.y;
    r.z = s * (az + bz2) + 0.1f * x.z;
    r.w = s * (aw + bw2) + 0.1f * x.w;
    *(float4*)(xc + (size_t)n * CC + lane * 4) = r;
}

// ---- K6: out = 0.5*xc + 0.5 * xc @ W^T  -- fp32, 128x64 tile, 8x4/thread
__global__ __launch_bounds__(256) void k6_gemm(const float* __restrict__ xc,
                                               const float* __restrict__ W,
                                               float* __restrict__ out) {
    __shared__ __align__(16) float As[16][132];   // [k][m], stride 132 (528B = 33*16)
    __shared__ __align__(16) float Bs[16][68];    // [k][n], stride 68  (272B = 17*16)
    const int bm = blockIdx.x * 128;
    const int bn = blockIdx.y * 64;
    const int t  = threadIdx.x;
    const int tx = t & 15;          // 16 col groups * 4
    const int ty = t >> 4;          // 16 row groups * 8
    float acc[8][4] = {};
    for (int k0 = 0; k0 < CC; k0 += 16) {
        #pragma unroll
        for (int l = 0; l < 2; ++l) {                  // A: 512 float4, 2/thread
            int q = t + l * 256;
            int r = q >> 2, ko = (q & 3) << 2;
            float4 v = *(const float4*)(xc + (size_t)(bm + r) * CC + k0 + ko);
            As[ko + 0][r] = v.x; As[ko + 1][r] = v.y; As[ko + 2][r] = v.z; As[ko + 3][r] = v.w;
        }
        {                                              // B: 256 float4, 1/thread
            int r = t >> 2, ko = (t & 3) << 2;
            float4 v = *(const float4*)(W + (size_t)(bn + r) * CC + k0 + ko);
            Bs[ko + 0][r] = v.x; Bs[ko + 1][r] = v.y; Bs[ko + 2][r] = v.z; Bs[ko + 3][r] = v.w;
        }
        __syncthreads();
        #pragma unroll
        for (int kk = 0; kk < 16; ++kk) {
            float a[8], b[4];
            *(float4*)(a)     = *(const float4*)&As[kk][ty * 8];
            *(float4*)(a + 4) = *(const float4*)&As[kk][ty * 8 + 4];
            *(float4*)(b)     = *(const float4*)&Bs[kk][tx * 4];
            #pragma unroll
            for (int ii = 0; ii < 8; ++ii)
                #pragma unroll
                for (int jj = 0; jj < 4; ++jj)
                    acc[ii][jj] += a[ii] * b[jj];
        }
        __syncthreads();
    }
    #pragma unroll
    for (int ii = 0; ii < 8; ++ii) {
        size_t r = bm + ty * 8 + ii;
        float4 sk = *(const float4*)(xc + r * CC + bn + tx * 4);
        float4 o;
        o.x = 0.5f * sk.x + 0.5f * acc[ii][0];
        o.y = 0.5f * sk.y + 0.5f * acc[ii][1];
        o.z = 0.5f * sk.z + 0.5f * acc[ii][2];
        o.w = 0.5f * sk.w + 0.5f * acc[ii][3];
        *(float4*)(out + r * CC + bn + tx * 4) = o;
    }
}

// ---- launch -----------------------------------------------------------------
extern "C" void kernel_launch(void* const* d_in, const int* in_sizes, int n_in,
                              void* d_out, int out_size, void* d_ws, size_t ws_size,
                              hipStream_t stream) {
    const float* x0 = (const float*)d_in[0];
    const float* B  = (const float*)d_in[1];
    const float* W  = (const float*)d_in[2];
    float* out = (float*)d_out;

    char* ws = (char*)d_ws;
    const size_t need = (24ull << 20) + 4ull * NE * 4;
    if (ws_size < need) return;

    int*   csr       = (int*)(ws);                   // 4 MB
    int*   csc       = (int*)(ws + (4ull << 20));    // 4 MB
    float* m01s      = (float*)(ws + (8ull << 20));  // 8 MB
    float* xc        = (float*)(ws + (16ull << 20)); // 8 MB
    int*   row_cnt   = (int*)(ws + (24ull << 20));   // 32 KB
    int*   col_cnt   = row_cnt + NN;                 // 32 KB (zeroed)
    float* edge_wsum = (float*)(col_cnt + NE);       // 32 KB (zeroed, adjacent)

    hipMemsetAsync(col_cnt, 0, 2ull * NE * 4, stream);   // col_cnt + edge_wsum

    k1_scan<<<NN / 4, 256, 0, stream>>>(B, csr, row_cnt, col_cnt, csc, edge_wsum);
    k4_edge_agg<<<NE / 4, 256, 0, stream>>>(x0, csc, col_cnt, edge_wsum, m01s);
    k5_node_agg<<<NN / 4, 256, 0, stream>>>(x0, m01s, csr, row_cnt, xc);
    dim3 g6(NN / 128, CC / 64);
    k6_gemm<<<g6, 256, 0, stream>>>(xc, W, out);
}

// Round 3
// 114.561 us; speedup vs baseline: 1.5708x; 1.2399x over previous
//
#include <hip/hip_runtime.h>
#include <hip/hip_bf16.h>

#define NN 8192   // nodes
#define NE 8192   // edges
#define CC 256    // channels
#define CAP 128   // max nnz per row/col (mean ~34, sigma ~5.7)

typedef __attribute__((ext_vector_type(8))) short bf16x8;
typedef __attribute__((ext_vector_type(4))) float f32x4;

static __device__ __forceinline__ ushort f2b(float f) {       // RNE f32->bf16
    unsigned u = __float_as_uint(f);
    return (ushort)((u + 0x7fffu + ((u >> 16) & 1u)) >> 16);
}
static __device__ __forceinline__ float b2f(ushort u) {
    return __uint_as_float((unsigned)u << 16);
}

// ---- K1: convert x0/W to bf16 (fused prologue), scan B rows -> CSR + row_cnt,
//          then scatter -> CSC + edge weighted-degree sums.
__global__ __launch_bounds__(256) void k1_scan(const float* __restrict__ B,
                                               const float* __restrict__ x0,
                                               const float* __restrict__ W,
                                               ushort* __restrict__ x0b,
                                               ushort* __restrict__ Wb,
                                               int* __restrict__ csr,
                                               int* __restrict__ row_cnt,
                                               int* __restrict__ col_cnt,
                                               int* __restrict__ csc,
                                               float* __restrict__ edge_wsum) {
    // fused conversions (x0: 2M elems over 2048 blocks; W: 64K elems over first 64)
    {
        int i = blockIdx.x * 1024 + threadIdx.x * 4;
        float4 v = *(const float4*)(x0 + i);
        ushort4 u; u.x = f2b(v.x); u.y = f2b(v.y); u.z = f2b(v.z); u.w = f2b(v.w);
        *(ushort4*)(x0b + i) = u;
        if (blockIdx.x < 64) {
            float4 w = *(const float4*)(W + i);
            ushort4 uw; uw.x = f2b(w.x); uw.y = f2b(w.y); uw.z = f2b(w.z); uw.w = f2b(w.w);
            *(ushort4*)(Wb + i) = uw;
        }
    }
    const int wave = threadIdx.x >> 6;
    const int lane = threadIdx.x & 63;
    const int row  = blockIdx.x * 4 + wave;
    const float4* rp = (const float4*)(B + (size_t)row * NE);
    int* outp = csr + (size_t)row * CAP;
    const unsigned long long mlt = (1ull << lane) - 1ull;
    int base = 0;
    for (int it = 0; it < NE / 256; ++it) {            // 32 iterations, 1 KB/wave each
        float4 v = rp[it * 64 + lane];
        unsigned long long bx = __ballot(v.x != 0.f);
        unsigned long long by = __ballot(v.y != 0.f);
        unsigned long long bz = __ballot(v.z != 0.f);
        unsigned long long bw = __ballot(v.w != 0.f);
        if (!(bx | by | bz | bw)) continue;
        int tx = __popcll(bx), ty = __popcll(by), tz = __popcll(bz), tw = __popcll(bw);
        int e0 = (it * 64 + lane) * 4;
        int p;
        if (v.x != 0.f) { p = base + __popcll(bx & mlt);                if (p < CAP) outp[p] = e0;     }
        if (v.y != 0.f) { p = base + tx + __popcll(by & mlt);           if (p < CAP) outp[p] = e0 + 1; }
        if (v.z != 0.f) { p = base + tx + ty + __popcll(bz & mlt);      if (p < CAP) outp[p] = e0 + 2; }
        if (v.w != 0.f) { p = base + tx + ty + tz + __popcll(bw & mlt); if (p < CAP) outp[p] = e0 + 3; }
        base += tx + ty + tz + tw;
    }
    const int cnt = base < CAP ? base : CAP;
    if (lane == 0) row_cnt[row] = cnt;
    const float deg = (float)cnt;
    for (int i = lane; i < cnt; i += 64) {
        int e = outp[i];
        int pos = atomicAdd(&col_cnt[e], 1);
        if (pos < CAP) csc[(size_t)e * CAP + pos] = row;
        atomicAdd(&edge_wsum[e], deg);                 // integer-valued: exact, order-free
    }
}

// ---- K4: m01s[e][:] = rsqrt(edge_deg) * sum_{n in col e} x0b[n][:]   (bf16 gather)
__global__ __launch_bounds__(256) void k4_edge_agg(const ushort* __restrict__ x0b,
                                                   const int* __restrict__ csc,
                                                   const int* __restrict__ col_cnt,
                                                   const float* __restrict__ edge_wsum,
                                                   ushort* __restrict__ m01s) {
    const int wave = threadIdx.x >> 6;
    const int lane = threadIdx.x & 63;
    const int e = blockIdx.x * 4 + wave;
    int cnt = col_cnt[e]; if (cnt > CAP) cnt = CAP;
    const float er = rsqrtf(edge_wsum[e] / (float)cnt);
    const int* cp = csc + (size_t)e * CAP;
    const int idx = cp[lane];
    const ushort* xb = x0b + lane * 4;
    float ax = 0.f, ay = 0.f, az = 0.f, aw = 0.f;
    float bx = 0.f, by = 0.f, bz = 0.f, bw = 0.f;
    const int lim = cnt < 64 ? cnt : 64;
    int i = 0;
    for (; i + 2 <= lim; i += 2) {
        int n0 = __shfl(idx, i), n1 = __shfl(idx, i + 1);
        ushort4 a = *(const ushort4*)(xb + (size_t)n0 * CC);
        ushort4 b = *(const ushort4*)(xb + (size_t)n1 * CC);
        ax += b2f(a.x); ay += b2f(a.y); az += b2f(a.z); aw += b2f(a.w);
        bx += b2f(b.x); by += b2f(b.y); bz += b2f(b.z); bw += b2f(b.w);
    }
    if (i < lim) {
        int n = __shfl(idx, i);
        ushort4 a = *(const ushort4*)(xb + (size_t)n * CC);
        ax += b2f(a.x); ay += b2f(a.y); az += b2f(a.z); aw += b2f(a.w);
    }
    for (int j = 64; j < cnt; ++j) {                   // vanishing probability
        int n = cp[j];
        ushort4 a = *(const ushort4*)(xb + (size_t)n * CC);
        ax += b2f(a.x); ay += b2f(a.y); az += b2f(a.z); aw += b2f(a.w);
    }
    ushort4 r;
    r.x = f2b((ax + bx) * er); r.y = f2b((ay + by) * er);
    r.z = f2b((az + bz) * er); r.w = f2b((aw + bw) * er);
    *(ushort4*)(m01s + (size_t)e * CC + lane * 4) = r;
}

// ---- K5: xcb[n][:] = bf16( 0.9*rsqrt(deg_n)*sum_{e in row n} m01s[e][:] + 0.1*x0b[n][:] )
__global__ __launch_bounds__(256) void k5_node_agg(const ushort* __restrict__ x0b,
                                                   const ushort* __restrict__ m01s,
                                                   const int* __restrict__ csr,
                                                   const int* __restrict__ row_cnt,
                                                   ushort* __restrict__ xcb) {
    const int wave = threadIdx.x >> 6;
    const int lane = threadIdx.x & 63;
    const int n = blockIdx.x * 4 + wave;
    const int cnt = row_cnt[n];
    const float nr = rsqrtf((float)cnt);
    const int* ep = csr + (size_t)n * CAP;
    const int idx = ep[lane];
    const ushort* mb = m01s + lane * 4;
    float ax = 0.f, ay = 0.f, az = 0.f, aw = 0.f;
    float bx = 0.f, by = 0.f, bz = 0.f, bw = 0.f;
    const int lim = cnt < 64 ? cnt : 64;
    int i = 0;
    for (; i + 2 <= lim; i += 2) {
        int e0 = __shfl(idx, i), e1 = __shfl(idx, i + 1);
        ushort4 a = *(const ushort4*)(mb + (size_t)e0 * CC);
        ushort4 b = *(const ushort4*)(mb + (size_t)e1 * CC);
        ax += b2f(a.x); ay += b2f(a.y); az += b2f(a.z); aw += b2f(a.w);
        bx += b2f(b.x); by += b2f(b.y); bz += b2f(b.z); bw += b2f(b.w);
    }
    if (i < lim) {
        int e0 = __shfl(idx, i);
        ushort4 a = *(const ushort4*)(mb + (size_t)e0 * CC);
        ax += b2f(a.x); ay += b2f(a.y); az += b2f(a.z); aw += b2f(a.w);
    }
    for (int j = 64; j < cnt; ++j) {
        int e0 = ep[j];
        ushort4 a = *(const ushort4*)(mb + (size_t)e0 * CC);
        ax += b2f(a.x); ay += b2f(a.y); az += b2f(a.z); aw += b2f(a.w);
    }
    ushort4 x = *(const ushort4*)(x0b + (size_t)n * CC + lane * 4);
    const float s = 0.9f * nr;
    ushort4 r;
    r.x = f2b(s * (ax + bx) + 0.1f * b2f(x.x));
    r.y = f2b(s * (ay + by) + 0.1f * b2f(x.y));
    r.z = f2b(s * (az + bz) + 0.1f * b2f(x.z));
    r.w = f2b(s * (aw + bw) + 0.1f * b2f(x.w));
    *(ushort4*)(xcb + (size_t)n * CC + lane * 4) = r;
}

// ---- K6: out = 0.5*xc + 0.5 * xc @ W^T  via mfma_f32_16x16x32_bf16, no LDS.
// Both operands row-major [*, K=256]: lane fragment = contiguous bf16x8 (m92 pattern).
// A lane map: row = l&15, k = (l>>4)*8 + e.  B lane map: col = l&15, same k.
// C/D (m89-verified): col = l&15, row = (l>>4)*4 + reg.
__global__ __launch_bounds__(256) void k6_gemm(const ushort* __restrict__ xcb,
                                               const ushort* __restrict__ Wb,
                                               float* __restrict__ out) {
    const int lane = threadIdx.x & 63;
    const int gw = blockIdx.x * 4 + (threadIdx.x >> 6);
    const int m0 = (gw >> 2) * 16;          // 512 row strips
    const int n0 = (gw & 3) * 64;           // 4 col strips of 64
    const int lr = lane & 15, lk = lane >> 4;
    f32x4 acc[4] = {};
    const ushort* ap = xcb + (size_t)(m0 + lr) * CC + lk * 8;
    #pragma unroll
    for (int kb = 0; kb < 8; ++kb) {
        bf16x8 a = *(const bf16x8*)(ap + kb * 32);
        #pragma unroll
        for (int j = 0; j < 4; ++j) {
            bf16x8 b = *(const bf16x8*)(Wb + (size_t)(n0 + j * 16 + lr) * CC + kb * 32 + lk * 8);
            acc[j] = __builtin_amdgcn_mfma_f32_16x16x32_bf16(a, b, acc[j], 0, 0, 0);
        }
    }
    #pragma unroll
    for (int j = 0; j < 4; ++j) {
        #pragma unroll
        for (int r = 0; r < 4; ++r) {
            int row = m0 + lk * 4 + r;
            int col = n0 + j * 16 + lr;
            float sk = b2f(xcb[(size_t)row * CC + col]);
            out[(size_t)row * CC + col] = 0.5f * sk + 0.5f * acc[j][r];
        }
    }
}

// ---- launch -----------------------------------------------------------------
extern "C" void kernel_launch(void* const* d_in, const int* in_sizes, int n_in,
                              void* d_out, int out_size, void* d_ws, size_t ws_size,
                              hipStream_t stream) {
    const float* x0 = (const float*)d_in[0];
    const float* B  = (const float*)d_in[1];
    const float* W  = (const float*)d_in[2];
    float* out = (float*)d_out;

    char* ws = (char*)d_ws;
    const size_t need = (21ull << 20) + 4ull * NE * 4;
    if (ws_size < need) return;

    int*    csr       = (int*)(ws);                    // 4 MB
    int*    csc       = (int*)(ws + (4ull << 20));     // 4 MB
    ushort* m01s      = (ushort*)(ws + (8ull << 20));  // 4 MB (bf16)
    ushort* xcb       = (ushort*)(ws + (12ull << 20)); // 4 MB (bf16)
    ushort* x0b       = (ushort*)(ws + (16ull << 20)); // 4 MB (bf16)
    ushort* Wb        = (ushort*)(ws + (20ull << 20)); // 128 KB (bf16)
    int*    row_cnt   = (int*)(ws + (20ull << 20) + (256u << 10)); // 32 KB
    int*    col_cnt   = row_cnt + NN;                  // 32 KB (zeroed)
    float*  edge_wsum = (float*)(col_cnt + NE);        // 32 KB (zeroed, adjacent)

    hipMemsetAsync(col_cnt, 0, 2ull * NE * 4, stream);

    k1_scan<<<NN / 4, 256, 0, stream>>>(B, x0, W, x0b, Wb, csr, row_cnt, col_cnt, csc, edge_wsum);
    k4_edge_agg<<<NE / 4, 256, 0, stream>>>(x0b, csc, col_cnt, edge_wsum, m01s);
    k5_node_agg<<<NN / 4, 256, 0, stream>>>(x0b, m01s, csr, row_cnt, xcb);
    k6_gemm<<<NN * CC / 16 / 64 / 4, 256, 0, stream>>>(xcb, Wb, out);
}

// Round 4
// 104.697 us; speedup vs baseline: 1.7187x; 1.0942x over previous
//
#include <hip/hip_runtime.h>
#include <hip/hip_bf16.h>

#define NN 8192   // nodes
#define NE 8192   // edges
#define CC 256    // channels
#define CAP 128   // max nnz per row/col (mean ~34, sigma ~5.7)

typedef __attribute__((ext_vector_type(8))) short bf16x8;
typedef __attribute__((ext_vector_type(8))) unsigned short u16x8;
typedef __attribute__((ext_vector_type(4))) float f32x4;

static __device__ __forceinline__ ushort f2b(float f) {       // RNE f32->bf16
    unsigned u = __float_as_uint(f);
    return (ushort)((u + 0x7fffu + ((u >> 16) & 1u)) >> 16);
}
static __device__ __forceinline__ float b2f(ushort u) {
    return __uint_as_float((unsigned)u << 16);
}

// ---- K1: convert x0/W to bf16 (fused prologue), scan B rows -> CSR + row_cnt,
//          then scatter -> CSC + edge weighted-degree sums.
__global__ __launch_bounds__(256) void k1_scan(const float* __restrict__ B,
                                               const float* __restrict__ x0,
                                               const float* __restrict__ W,
                                               ushort* __restrict__ x0b,
                                               ushort* __restrict__ Wb,
                                               int* __restrict__ csr,
                                               int* __restrict__ row_cnt,
                                               int* __restrict__ col_cnt,
                                               int* __restrict__ csc,
                                               float* __restrict__ edge_wsum) {
    {
        int i = blockIdx.x * 1024 + threadIdx.x * 4;
        float4 v = *(const float4*)(x0 + i);
        ushort4 u; u.x = f2b(v.x); u.y = f2b(v.y); u.z = f2b(v.z); u.w = f2b(v.w);
        *(ushort4*)(x0b + i) = u;
        if (blockIdx.x < 64) {
            float4 w = *(const float4*)(W + i);
            ushort4 uw; uw.x = f2b(w.x); uw.y = f2b(w.y); uw.z = f2b(w.z); uw.w = f2b(w.w);
            *(ushort4*)(Wb + i) = uw;
        }
    }
    const int wave = threadIdx.x >> 6;
    const int lane = threadIdx.x & 63;
    const int row  = blockIdx.x * 4 + wave;
    const float4* rp = (const float4*)(B + (size_t)row * NE);
    int* outp = csr + (size_t)row * CAP;
    const unsigned long long mlt = (1ull << lane) - 1ull;
    int base = 0;
    for (int it = 0; it < NE / 256; ++it) {            // 32 iterations, 1 KB/wave each
        float4 v = rp[it * 64 + lane];
        unsigned long long bx = __ballot(v.x != 0.f);
        unsigned long long by = __ballot(v.y != 0.f);
        unsigned long long bz = __ballot(v.z != 0.f);
        unsigned long long bw = __ballot(v.w != 0.f);
        if (!(bx | by | bz | bw)) continue;
        int tx = __popcll(bx), ty = __popcll(by), tz = __popcll(bz), tw = __popcll(bw);
        int e0 = (it * 64 + lane) * 4;
        int p;
        if (v.x != 0.f) { p = base + __popcll(bx & mlt);                if (p < CAP) outp[p] = e0;     }
        if (v.y != 0.f) { p = base + tx + __popcll(by & mlt);           if (p < CAP) outp[p] = e0 + 1; }
        if (v.z != 0.f) { p = base + tx + ty + __popcll(bz & mlt);      if (p < CAP) outp[p] = e0 + 2; }
        if (v.w != 0.f) { p = base + tx + ty + tz + __popcll(bw & mlt); if (p < CAP) outp[p] = e0 + 3; }
        base += tx + ty + tz + tw;
    }
    const int cnt = base < CAP ? base : CAP;
    if (lane == 0) row_cnt[row] = cnt;
    const float deg = (float)cnt;
    for (int i = lane; i < cnt; i += 64) {
        int e = outp[i];
        int pos = atomicAdd(&col_cnt[e], 1);
        if (pos < CAP) csc[(size_t)e * CAP + pos] = row;
        atomicAdd(&edge_wsum[e], deg);                 // integer-valued: exact, order-free
    }
}

// ---- K4: m01s[e][:] = rsqrt(edge_deg) * sum_{n in col e} x0b[n][:]
// 16 B/lane: half-wave covers a full 512 B row -> 2 rows per load instruction.
__global__ __launch_bounds__(256) void k4_edge_agg(const ushort* __restrict__ x0b,
                                                   const int* __restrict__ csc,
                                                   const int* __restrict__ col_cnt,
                                                   const float* __restrict__ edge_wsum,
                                                   ushort* __restrict__ m01s) {
    const int wave = threadIdx.x >> 6;
    const int lane = threadIdx.x & 63;
    const int half = lane >> 5;
    const int cl = lane & 31;
    const int e = blockIdx.x * 4 + wave;
    int cnt = col_cnt[e]; if (cnt > CAP) cnt = CAP;
    const float er = rsqrtf(edge_wsum[e] / (float)cnt);
    const int* cp = csc + (size_t)e * CAP;
    const int idx = cp[lane];                          // first 64 indices in-register
    const ushort* xb = x0b + cl * 8;
    float a0[8] = {}, a1[8] = {};
    const int lim = cnt < 64 ? cnt : 64;
    int i = 0;
    for (; i + 4 <= lim; i += 4) {
        int na = __shfl(idx, i + half);
        int nb = __shfl(idx, i + 2 + half);
        u16x8 a = *(const u16x8*)(xb + (size_t)na * CC);
        u16x8 b = *(const u16x8*)(xb + (size_t)nb * CC);
        #pragma unroll
        for (int c = 0; c < 8; ++c) { a0[c] += b2f(a[c]); a1[c] += b2f(b[c]); }
    }
    if (i + 2 <= lim) {
        int na = __shfl(idx, i + half);
        u16x8 a = *(const u16x8*)(xb + (size_t)na * CC);
        #pragma unroll
        for (int c = 0; c < 8; ++c) a0[c] += b2f(a[c]);
        i += 2;
    }
    if (i < lim) {
        int na = __shfl(idx, i);                       // shfl before divergence
        if (half == 0) {
            u16x8 a = *(const u16x8*)(xb + (size_t)na * CC);
            #pragma unroll
            for (int c = 0; c < 8; ++c) a0[c] += b2f(a[c]);
        }
    }
    if (cnt > 64 && half == 0) {                       // vanishing probability
        for (int j = 64; j < cnt; ++j) {
            int n2 = cp[j];
            u16x8 a = *(const u16x8*)(xb + (size_t)n2 * CC);
            #pragma unroll
            for (int c = 0; c < 8; ++c) a0[c] += b2f(a[c]);
        }
    }
    u16x8 r8;
    #pragma unroll
    for (int c = 0; c < 8; ++c) {
        float t = a0[c] + a1[c];
        t += __shfl_xor(t, 32);
        r8[c] = f2b(t * er);
    }
    if (half == 0) *(u16x8*)(m01s + (size_t)e * CC + cl * 8) = r8;
}

// ---- K5': fused node aggregation + skip + GEMM epilogue.
// Block = 16 nodes, 16 waves (1024 thr). Wave w: gather xc row w -> LDS (bf16,
// padded stride 264 -> rows advance banks by 4 -> 2-way = free). Sync. Then
// wave w computes out[0:16][w*16:(w+1)*16] = 0.5*xc + 0.5*xc@W^T via 8 MFMAs.
__global__ __launch_bounds__(1024, 8) void k5_fused(const ushort* __restrict__ x0b,
                                                    const ushort* __restrict__ m01s,
                                                    const int* __restrict__ csr,
                                                    const int* __restrict__ row_cnt,
                                                    const ushort* __restrict__ Wb,
                                                    float* __restrict__ out) {
    __shared__ __align__(16) ushort xs[16][264];
    const int w = threadIdx.x >> 6;
    const int lane = threadIdx.x & 63;
    const int half = lane >> 5;
    const int cl = lane & 31;
    const int n = blockIdx.x * 16 + w;
    const int cnt = row_cnt[n];
    const float nr = rsqrtf((float)cnt);
    const int* ep = csr + (size_t)n * CAP;
    const int idx = ep[lane];
    const ushort* mb = m01s + cl * 8;
    float a0[8] = {}, a1[8] = {};
    const int lim = cnt < 64 ? cnt : 64;
    int i = 0;
    for (; i + 4 <= lim; i += 4) {
        int ea = __shfl(idx, i + half);
        int eb = __shfl(idx, i + 2 + half);
        u16x8 a = *(const u16x8*)(mb + (size_t)ea * CC);
        u16x8 b = *(const u16x8*)(mb + (size_t)eb * CC);
        #pragma unroll
        for (int c = 0; c < 8; ++c) { a0[c] += b2f(a[c]); a1[c] += b2f(b[c]); }
    }
    if (i + 2 <= lim) {
        int ea = __shfl(idx, i + half);
        u16x8 a = *(const u16x8*)(mb + (size_t)ea * CC);
        #pragma unroll
        for (int c = 0; c < 8; ++c) a0[c] += b2f(a[c]);
        i += 2;
    }
    if (i < lim) {
        int ea = __shfl(idx, i);
        if (half == 0) {
            u16x8 a = *(const u16x8*)(mb + (size_t)ea * CC);
            #pragma unroll
            for (int c = 0; c < 8; ++c) a0[c] += b2f(a[c]);
        }
    }
    if (cnt > 64 && half == 0) {
        for (int j = 64; j < cnt; ++j) {
            int e2 = ep[j];
            u16x8 a = *(const u16x8*)(mb + (size_t)e2 * CC);
            #pragma unroll
            for (int c = 0; c < 8; ++c) a0[c] += b2f(a[c]);
        }
    }
    u16x8 x = *(const u16x8*)(x0b + (size_t)n * CC + cl * 8);
    const float s = 0.9f * nr;
    u16x8 r8;
    #pragma unroll
    for (int c = 0; c < 8; ++c) {
        float t = a0[c] + a1[c];
        t += __shfl_xor(t, 32);
        r8[c] = f2b(s * t + 0.1f * b2f(x[c]));
    }
    if (half == 0) *(u16x8*)(&xs[w][cl * 8]) = r8;
    __syncthreads();
    // ---- MFMA epilogue: A = xs (16 rows), B = W col-strip [w*16, w*16+16)
    const int lr = lane & 15, lk = lane >> 4;
    const int n0 = w * 16;
    f32x4 acc = {0.f, 0.f, 0.f, 0.f};
    #pragma unroll
    for (int kb = 0; kb < 8; ++kb) {
        bf16x8 a = *(const bf16x8*)(&xs[lr][kb * 32 + lk * 8]);
        bf16x8 b = *(const bf16x8*)(Wb + (size_t)(n0 + lr) * CC + kb * 32 + lk * 8);
        acc = __builtin_amdgcn_mfma_f32_16x16x32_bf16(a, b, acc, 0, 0, 0);
    }
    const size_t rb = (size_t)blockIdx.x * 16;
    #pragma unroll
    for (int r = 0; r < 4; ++r) {
        int row = lk * 4 + r;                      // C/D: col=lane&15, row=(lane>>4)*4+reg
        int col = n0 + lr;
        float sk = b2f(xs[row][col]);
        out[(rb + row) * CC + col] = 0.5f * sk + 0.5f * acc[r];
    }
}

// ---- launch -----------------------------------------------------------------
extern "C" void kernel_launch(void* const* d_in, const int* in_sizes, int n_in,
                              void* d_out, int out_size, void* d_ws, size_t ws_size,
                              hipStream_t stream) {
    const float* x0 = (const float*)d_in[0];
    const float* B  = (const float*)d_in[1];
    const float* W  = (const float*)d_in[2];
    float* out = (float*)d_out;

    char* ws = (char*)d_ws;
    const size_t need = (17ull << 20) + 4ull * NE * 4;
    if (ws_size < need) return;

    int*    csr       = (int*)(ws);                    // 4 MB
    int*    csc       = (int*)(ws + (4ull << 20));     // 4 MB
    ushort* m01s      = (ushort*)(ws + (8ull << 20));  // 4 MB (bf16)
    ushort* x0b       = (ushort*)(ws + (12ull << 20)); // 4 MB (bf16)
    ushort* Wb        = (ushort*)(ws + (16ull << 20)); // 128 KB (bf16)
    int*    row_cnt   = (int*)(ws + (16ull << 20) + (256u << 10)); // 32 KB
    int*    col_cnt   = row_cnt + NN;                  // 32 KB (zeroed)
    float*  edge_wsum = (float*)(col_cnt + NE);        // 32 KB (zeroed, adjacent)

    hipMemsetAsync(col_cnt, 0, 2ull * NE * 4, stream);

    k1_scan<<<NN / 4, 256, 0, stream>>>(B, x0, W, x0b, Wb, csr, row_cnt, col_cnt, csc, edge_wsum);
    k4_edge_agg<<<NE / 4, 256, 0, stream>>>(x0b, csc, col_cnt, edge_wsum, m01s);
    k5_fused<<<NN / 16, 1024, 0, stream>>>(x0b, m01s, csr, row_cnt, Wb, out);
}

// Round 5
// 103.808 us; speedup vs baseline: 1.7335x; 1.0086x over previous
//
#include <hip/hip_runtime.h>
#include <hip/hip_bf16.h>

#define NN 8192   // nodes
#define NE 8192   // edges
#define CC 256    // channels
#define CAP 128   // max nnz per row/col (mean ~34, sigma ~5.7)

typedef __attribute__((ext_vector_type(8))) short bf16x8;
typedef __attribute__((ext_vector_type(8))) unsigned short u16x8;
typedef __attribute__((ext_vector_type(4))) float f32x4;

static __device__ __forceinline__ ushort f2b(float f) {       // RNE f32->bf16
    unsigned u = __float_as_uint(f);
    return (ushort)((u + 0x7fffu + ((u >> 16) & 1u)) >> 16);
}
static __device__ __forceinline__ float b2f(ushort u) {
    return __uint_as_float((unsigned)u << 16);
}

// ---- K1: convert x0/W to bf16 (fused prologue), scan B rows -> CSR + row_cnt
// (binary incidence: LDS-atomic slot allocation instead of ballot-prefix),
// then scatter -> CSC + edge weighted-degree sums.
__global__ __launch_bounds__(256) void k1_scan(const float* __restrict__ B,
                                               const float* __restrict__ x0,
                                               const float* __restrict__ W,
                                               ushort* __restrict__ x0b,
                                               ushort* __restrict__ Wb,
                                               int* __restrict__ csr,
                                               int* __restrict__ row_cnt,
                                               int* __restrict__ col_cnt,
                                               int* __restrict__ csc,
                                               float* __restrict__ edge_wsum) {
    __shared__ int wcnt[4];
    {
        int i = blockIdx.x * 1024 + threadIdx.x * 4;
        float4 v = *(const float4*)(x0 + i);
        ushort4 u; u.x = f2b(v.x); u.y = f2b(v.y); u.z = f2b(v.z); u.w = f2b(v.w);
        *(ushort4*)(x0b + i) = u;
        if (blockIdx.x < 64) {
            float4 w = *(const float4*)(W + i);
            ushort4 uw; uw.x = f2b(w.x); uw.y = f2b(w.y); uw.z = f2b(w.z); uw.w = f2b(w.w);
            *(ushort4*)(Wb + i) = uw;
        }
    }
    const int wave = threadIdx.x >> 6;
    const int lane = threadIdx.x & 63;
    const int row  = blockIdx.x * 4 + wave;
    const float4* rp = (const float4*)(B + (size_t)row * NE);
    int* outp = csr + (size_t)row * CAP;
    if (lane == 0) wcnt[wave] = 0;          // per-wave private counter; ds ops in-order
    float4 v = rp[lane];
    #pragma unroll 1
    for (int it = 0; it < 32; ++it) {       // 32 iterations, 1 KB/wave, 2-deep pipeline
        float4 vn = v;
        if (it < 31) vn = rp[(it + 1) * 64 + lane];
        float fs = v.x + v.y + v.z + v.w;   // binary entries: fs = #nonzero as float
        if (__ballot(fs != 0.f)) {
            int m = (int)fs;
            int pos = 0;
            if (m) pos = atomicAdd(&wcnt[wave], m);
            int e0 = (it * 64 + lane) * 4;
            if (v.x != 0.f) { if (pos < CAP) outp[pos] = e0;     ++pos; }
            if (v.y != 0.f) { if (pos < CAP) outp[pos] = e0 + 1; ++pos; }
            if (v.z != 0.f) { if (pos < CAP) outp[pos] = e0 + 2; ++pos; }
            if (v.w != 0.f) { if (pos < CAP) outp[pos] = e0 + 3; ++pos; }
        }
        v = vn;
    }
    int cnt = wcnt[wave];                   // same-wave ds read: ordered after atomics
    cnt = cnt < CAP ? cnt : CAP;
    if (lane == 0) row_cnt[row] = cnt;
    const float deg = (float)cnt;
    for (int i = lane; i < cnt; i += 64) {
        int e = outp[i];
        int pos = atomicAdd(&col_cnt[e], 1);
        if (pos < CAP) csc[(size_t)e * CAP + pos] = row;
        atomicAdd(&edge_wsum[e], deg);      // integer-valued: exact, order-free
    }
}

// ---- K4: m01s[e][:] = rsqrt(edge_deg) * sum_{n in col e} x0b[n][:]
// 16 B/lane, half-wave = one 512 B row; 4 loads (8 rows) in flight per iteration.
__global__ __launch_bounds__(256) void k4_edge_agg(const ushort* __restrict__ x0b,
                                                   const int* __restrict__ csc,
                                                   const int* __restrict__ col_cnt,
                                                   const float* __restrict__ edge_wsum,
                                                   ushort* __restrict__ m01s) {
    const int wave = threadIdx.x >> 6;
    const int lane = threadIdx.x & 63;
    const int half = lane >> 5;
    const int cl = lane & 31;
    const int e = blockIdx.x * 4 + wave;
    int cnt = col_cnt[e]; if (cnt > CAP) cnt = CAP;
    const float er = rsqrtf(edge_wsum[e] / (float)cnt);
    const int* cp = csc + (size_t)e * CAP;
    const int idx = cp[lane];                          // first 64 indices in-register
    const ushort* xb = x0b + cl * 8;
    float a0[8] = {}, a1[8] = {};
    const int lim = cnt < 64 ? cnt : 64;
    int i = 0;
    for (; i + 8 <= lim; i += 8) {
        int n0 = __shfl(idx, i + half);
        int n1 = __shfl(idx, i + 2 + half);
        int n2 = __shfl(idx, i + 4 + half);
        int n3 = __shfl(idx, i + 6 + half);
        u16x8 r0 = *(const u16x8*)(xb + (size_t)n0 * CC);
        u16x8 r1 = *(const u16x8*)(xb + (size_t)n1 * CC);
        u16x8 r2 = *(const u16x8*)(xb + (size_t)n2 * CC);
        u16x8 r3 = *(const u16x8*)(xb + (size_t)n3 * CC);
        #pragma unroll
        for (int c = 0; c < 8; ++c) {
            a0[c] += b2f(r0[c]); a1[c] += b2f(r1[c]);
            a0[c] += b2f(r2[c]); a1[c] += b2f(r3[c]);
        }
    }
    for (; i + 2 <= lim; i += 2) {
        int n0 = __shfl(idx, i + half);
        u16x8 r0 = *(const u16x8*)(xb + (size_t)n0 * CC);
        #pragma unroll
        for (int c = 0; c < 8; ++c) a0[c] += b2f(r0[c]);
    }
    if (i < lim) {
        int n0 = __shfl(idx, i);                       // shfl before divergence
        if (half == 0) {
            u16x8 r0 = *(const u16x8*)(xb + (size_t)n0 * CC);
            #pragma unroll
            for (int c = 0; c < 8; ++c) a0[c] += b2f(r0[c]);
        }
    }
    if (cnt > 64 && half == 0) {                       // vanishing probability
        for (int j = 64; j < cnt; ++j) {
            int n2 = cp[j];
            u16x8 r0 = *(const u16x8*)(xb + (size_t)n2 * CC);
            #pragma unroll
            for (int c = 0; c < 8; ++c) a0[c] += b2f(r0[c]);
        }
    }
    u16x8 r8;
    #pragma unroll
    for (int c = 0; c < 8; ++c) {
        float t = a0[c] + a1[c];
        t += __shfl_xor(t, 32);
        r8[c] = f2b(t * er);
    }
    if (half == 0) *(u16x8*)(m01s + (size_t)e * CC + cl * 8) = r8;
}

// ---- K5': fused node aggregation + skip + GEMM epilogue.
// Block = 16 nodes, 16 waves (1024 thr). Wave w gathers row w -> LDS (bf16,
// stride 264: rows advance banks by 4 -> 2-way = free). Sync. Wave w then
// computes out[0:16][w*16:(w+1)*16] = 0.5*xc + 0.5*xc@W^T via 8 MFMAs.
__global__ __launch_bounds__(1024, 8) void k5_fused(const ushort* __restrict__ x0b,
                                                    const ushort* __restrict__ m01s,
                                                    const int* __restrict__ csr,
                                                    const int* __restrict__ row_cnt,
                                                    const ushort* __restrict__ Wb,
                                                    float* __restrict__ out) {
    __shared__ __align__(16) ushort xs[16][264];
    const int w = threadIdx.x >> 6;
    const int lane = threadIdx.x & 63;
    const int half = lane >> 5;
    const int cl = lane & 31;
    const int n = blockIdx.x * 16 + w;
    const int cnt = row_cnt[n];
    const float nr = rsqrtf((float)cnt);
    const int* ep = csr + (size_t)n * CAP;
    const int idx = ep[lane];
    const ushort* mb = m01s + cl * 8;
    float a0[8] = {}, a1[8] = {};
    const int lim = cnt < 64 ? cnt : 64;
    int i = 0;
    for (; i + 8 <= lim; i += 8) {
        int e0 = __shfl(idx, i + half);
        int e1 = __shfl(idx, i + 2 + half);
        int e2 = __shfl(idx, i + 4 + half);
        int e3 = __shfl(idx, i + 6 + half);
        u16x8 r0 = *(const u16x8*)(mb + (size_t)e0 * CC);
        u16x8 r1 = *(const u16x8*)(mb + (size_t)e1 * CC);
        u16x8 r2 = *(const u16x8*)(mb + (size_t)e2 * CC);
        u16x8 r3 = *(const u16x8*)(mb + (size_t)e3 * CC);
        #pragma unroll
        for (int c = 0; c < 8; ++c) {
            a0[c] += b2f(r0[c]); a1[c] += b2f(r1[c]);
            a0[c] += b2f(r2[c]); a1[c] += b2f(r3[c]);
        }
    }
    for (; i + 2 <= lim; i += 2) {
        int e0 = __shfl(idx, i + half);
        u16x8 r0 = *(const u16x8*)(mb + (size_t)e0 * CC);
        #pragma unroll
        for (int c = 0; c < 8; ++c) a0[c] += b2f(r0[c]);
    }
    if (i < lim) {
        int e0 = __shfl(idx, i);
        if (half == 0) {
            u16x8 r0 = *(const u16x8*)(mb + (size_t)e0 * CC);
            #pragma unroll
            for (int c = 0; c < 8; ++c) a0[c] += b2f(r0[c]);
        }
    }
    if (cnt > 64 && half == 0) {
        for (int j = 64; j < cnt; ++j) {
            int e2 = ep[j];
            u16x8 r0 = *(const u16x8*)(mb + (size_t)e2 * CC);
            #pragma unroll
            for (int c = 0; c < 8; ++c) a0[c] += b2f(r0[c]);
        }
    }
    u16x8 x = *(const u16x8*)(x0b + (size_t)n * CC + cl * 8);
    const float s = 0.9f * nr;
    u16x8 r8;
    #pragma unroll
    for (int c = 0; c < 8; ++c) {
        float t = a0[c] + a1[c];
        t += __shfl_xor(t, 32);
        r8[c] = f2b(s * t + 0.1f * b2f(x[c]));
    }
    if (half == 0) *(u16x8*)(&xs[w][cl * 8]) = r8;
    __syncthreads();
    // ---- MFMA epilogue: A = xs (16 rows), B = W col-strip [w*16, w*16+16)
    const int lr = lane & 15, lk = lane >> 4;
    const int n0 = w * 16;
    f32x4 acc = {0.f, 0.f, 0.f, 0.f};
    #pragma unroll
    for (int kb = 0; kb < 8; ++kb) {
        bf16x8 a = *(const bf16x8*)(&xs[lr][kb * 32 + lk * 8]);
        bf16x8 b = *(const bf16x8*)(Wb + (size_t)(n0 + lr) * CC + kb * 32 + lk * 8);
        acc = __builtin_amdgcn_mfma_f32_16x16x32_bf16(a, b, acc, 0, 0, 0);
    }
    const size_t rb = (size_t)blockIdx.x * 16;
    #pragma unroll
    for (int r = 0; r < 4; ++r) {
        int row = lk * 4 + r;                      // C/D: col=lane&15, row=(lane>>4)*4+reg
        int col = n0 + lr;
        float sk = b2f(xs[row][col]);
        out[(rb + row) * CC + col] = 0.5f * sk + 0.5f * acc[r];
    }
}

// ---- launch -----------------------------------------------------------------
extern "C" void kernel_launch(void* const* d_in, const int* in_sizes, int n_in,
                              void* d_out, int out_size, void* d_ws, size_t ws_size,
                              hipStream_t stream) {
    const float* x0 = (const float*)d_in[0];
    const float* B  = (const float*)d_in[1];
    const float* W  = (const float*)d_in[2];
    float* out = (float*)d_out;

    char* ws = (char*)d_ws;
    const size_t need = (17ull << 20) + 4ull * NE * 4;
    if (ws_size < need) return;

    int*    csr       = (int*)(ws);                    // 4 MB
    int*    csc       = (int*)(ws + (4ull << 20));     // 4 MB
    ushort* m01s      = (ushort*)(ws + (8ull << 20));  // 4 MB (bf16)
    ushort* x0b       = (ushort*)(ws + (12ull << 20)); // 4 MB (bf16)
    ushort* Wb        = (ushort*)(ws + (16ull << 20)); // 128 KB (bf16)
    int*    row_cnt   = (int*)(ws + (16ull << 20) + (256u << 10)); // 32 KB
    int*    col_cnt   = row_cnt + NN;                  // 32 KB (zeroed)
    float*  edge_wsum = (float*)(col_cnt + NE);        // 32 KB (zeroed, adjacent)

    hipMemsetAsync(col_cnt, 0, 2ull * NE * 4, stream);

    k1_scan<<<NN / 4, 256, 0, stream>>>(B, x0, W, x0b, Wb, csr, row_cnt, col_cnt, csc, edge_wsum);
    k4_edge_agg<<<NE / 4, 256, 0, stream>>>(x0b, csc, col_cnt, edge_wsum, m01s);
    k5_fused<<<NN / 16, 1024, 0, stream>>>(x0b, m01s, csr, row_cnt, Wb, out);
}